// Round 11
// baseline (566.152 us; speedup 1.0000x reference)
//
#include <hip/hip_runtime.h>
#include <hip/hip_bf16.h>

using uint32   = unsigned int;
using ushort_t = unsigned short;
using short8   = __attribute__((ext_vector_type(8))) short;
using uint4v   = __attribute__((ext_vector_type(4))) uint32;
using float4v  = __attribute__((ext_vector_type(4))) float;
using floatx16 = __attribute__((ext_vector_type(16))) float;

#define M_DIM 32
#define K_DIM 8192
#define N_DIM 28672
#define QROW  (N_DIM/8)   /* 3584 dwords per qweight k-row */
#define KSPLIT 16
#define BN    256         /* full 128B cache line per staged k-row */
#define NB    (N_DIM/BN)  /* 112 n-blocks */
#define CH    128         /* k per chunk == QGS */
#define NCH   4           /* chunks per block (K_DIM / KSPLIT / CH) */
#define TDW   32          /* panel width in dwords (256 n / 8) */

typedef __attribute__((address_space(3))) uint32 lds_u32;
typedef const __attribute__((address_space(1))) uint32 glb_u32;

__device__ ushort_t g_xr2[M_DIM * K_DIM]; // rotated x, k-octet-major MFMA-A order
__device__ float    g_S[64 * M_DIM];      // per-group row sums of bf16(xr)

__device__ __forceinline__ float bf2f(ushort_t u){
  unsigned int v = ((unsigned int)u) << 16;
  return __builtin_bit_cast(float, v);
}
__device__ __forceinline__ ushort_t f2bf(float f){
  return __builtin_bit_cast(ushort_t, __float2bfloat16(f)); // RNE
}

// ------------- prep: rotation + group sums, and bias broadcast ---------
__global__ __launch_bounds__(256) void prep_kernel(
    const float* __restrict__ x, const float* __restrict__ theta,
    const int* __restrict__ pairs, const float* __restrict__ cs,
    const float* __restrict__ bias, float* __restrict__ out)
{
  if (blockIdx.x >= 512){
    const int b  = blockIdx.x - 512;
    const int n  = (b % (N_DIM/256))*256 + threadIdx.x;
    const int m0 = (b / (N_DIM/256))*8;
    const float bv = bias[n];
    #pragma unroll
    for (int m = 0; m < 8; ++m) out[(size_t)(m0+m)*N_DIM + n] = bv;
    return;
  }
  __shared__ float xb[4][128];
  const int u    = threadIdx.x >> 6;
  const int lane = threadIdx.x & 63;
  const int id   = blockIdx.x * 4 + u;   // 0..2047 = m*64+g
  const int m    = id >> 6;
  const int g    = id & 63;
  const float* xp = x + m*K_DIM + g*128;
  int   ip[8], jp[8];
  float cv[8], sv[8];
  #pragma unroll
  for (int k = 0; k < 8; ++k){
    ip[k] = pairs[k*128 + 2*lane];
    jp[k] = pairs[k*128 + 2*lane + 1];
    const float th = theta[k*(K_DIM/2) + g*64 + lane];
    cv[k] = cosf(th); sv[k] = sinf(th);
  }
  xb[u][lane]    = xp[lane];
  xb[u][lane+64] = xp[lane+64];
  #pragma unroll
  for (int k = 0; k < 8; ++k){
    __syncthreads();
    const float xi = xb[u][ip[k]], xj = xb[u][jp[k]];
    xb[u][ip[k]] = cv[k]*xi - sv[k]*xj;
    xb[u][jp[k]] = sv[k]*xi + cv[k]*xj;
  }
  __syncthreads();
  const int base = g*128;
  const int k0 = base + lane, k1 = base + lane + 64;
  const ushort_t b0 = f2bf(xb[u][lane]    * cs[k0]);
  const ushort_t b1 = f2bf(xb[u][lane+64] * cs[k1]);
  g_xr2[(((size_t)(k0>>3))*32 + m)*8 + (k0&7)] = b0;
  g_xr2[(((size_t)(k1>>3))*32 + m)*8 + (k1&7)] = b1;
  float sum = bf2f(b0) + bf2f(b1);
  #pragma unroll
  for (int d = 32; d > 0; d >>= 1) sum += __shfl_xor(sum, d, 64);
  if (lane == 0) g_S[g*M_DIM + m] = sum;
}

// ---- GEMM: BN=256, full-line B staging, pinned global_load_lds -------
// Per staging inst: 8 k-rows x 128B contiguous = full cache lines (the
// one dimension never varied across the 75-80us plateau: previous rounds
// fetched 64B half-lines at 14KB stride). Wave owns 64 n-cols (2 B-tiles);
// A-frags shared across both -> 2x arithmetic intensity per staged byte.
// Depth-1 pinned staging: stage(c+1) issued at chunk-c top (un-sinkable
// intrinsic), vmcnt(0)+lgkm(0) barrier at chunk end.
__global__ __launch_bounds__(256, 4) void gemm_kernel(
    const uint32* __restrict__ qw, const uint32* __restrict__ qz,
    const float* __restrict__ scales, float* __restrict__ out)
{
  __shared__ uint32 T[2][CH*TDW];           // 2 x 16 KB B-chunk panels
  const int bid  = blockIdx.x;
  const int ks   = bid & (KSPLIT-1);        // bid%8 = ks%8 -> same-ks blocks
  const int nb   = bid >> 4;                //   cluster per XCD (A-slice reuse)
  const int tid  = threadIdx.x;
  const int w    = tid >> 6;                // 0..3
  const int lane = tid & 63;
  const int l31  = lane & 31;
  const int koct = lane >> 5;
  const int n0   = nb * BN;
  const uint32 sh = (uint32)((l31 & 7)*4);
  const int colw = w*8 + (l31 >> 3);        // dword col base (sub adds +4)
  const int k0   = ks * (NCH*CH);           // 512*ks

  // staging per-lane source: row w*8+(lane>>3), 16B unit (lane&7)*4 dwords
  const int trow = w*8 + (lane >> 3);       // 0..31 (q adds q*32)
  const int tcol = (lane & 7)*4;
  const uint32* sbase = qw + (size_t)(k0 + trow)*QROW + (n0>>3) + tcol;
  const ushort_t* abase = g_xr2 + (size_t)k0*32;

  auto stage = [&](int c, int b){
    #pragma unroll
    for (int q = 0; q < 4; ++q){            // rows q*32+w*8 .. +7, 128B each
      const uint32* gp = sbase + (size_t)(c*CH + q*32)*QROW;
      lds_u32* lp = (lds_u32*)&T[b][q*1024 + w*256]; // wave-uniform; HW adds lane*16B
      __builtin_amdgcn_global_load_lds((glb_u32*)gp, lp, 16, 0, 0);
    }
  };

  float accT[2][16];
  #pragma unroll
  for (int s2 = 0; s2 < 2; ++s2)
    #pragma unroll
    for (int r = 0; r < 16; ++r) accT[s2][r] = 0.f;

  // prelude: stage chunk 0, wait, barrier
  stage(0, 0);
  asm volatile("s_waitcnt vmcnt(0)" ::: "memory");
  __builtin_amdgcn_s_barrier();
  asm volatile("" ::: "memory");

  #pragma unroll
  for (int c = 0; c < NCH; ++c){
    const int cb = c & 1, nx = cb ^ 1;
    // per-chunk scalars for both subs (issue early)
    float  sc[2]; uint32 zc[2];
    #pragma unroll
    for (int s2 = 0; s2 < 2; ++s2){
      const int nn = n0 + w*64 + s2*32 + l31;
      sc[s2] = scales[(size_t)(ks*NCH + c)*N_DIM + nn];
      zc[s2] = qz[(size_t)(ks*NCH + c)*QROW + (nn>>3)];
    }
    if (c + 1 < NCH) stage(c + 1, nx);      // pinned issue; lands during compute

    const ushort_t* ab = abase + (size_t)c*CH*32;
    const uint32* Tc = &T[cb][0];
    const float* Sg = &g_S[(size_t)(ks*NCH + c)*M_DIM];

    #pragma unroll
    for (int s2 = 0; s2 < 2; ++s2){
      floatx16 acc;
      #pragma unroll
      for (int r = 0; r < 16; ++r) acc[r] = 0.f;
      const int cs2 = colw + s2*4;
      #pragma unroll
      for (int kh = 0; kh < 2; ++kh){       // A reloaded per sub (L1-hot)
        short8 av[4];
        #pragma unroll
        for (int i = 0; i < 4; ++i){
          const int kk = kh*4 + i;
          av[i] = *(const short8*)(ab + ((kk*2 + koct)*32 + l31)*8);
        }
        #pragma unroll
        for (int i = 0; i < 4; ++i){
          const int kk = kh*4 + i;
          const int rb = kk*16 + koct*8;
          uint32 p[8];
          #pragma unroll
          for (int j = 0; j < 8; ++j) p[j] = Tc[(rb + j)*TDW + cs2];
          // mask BEFORE merge (r5's merged form OR-corrupted nibbles)
          uint4v bp;
          bp.x = ((p[0] >> sh) & 15u) | (((p[1] >> sh) & 15u) << 16) | 0x43004300u;
          bp.y = ((p[2] >> sh) & 15u) | (((p[3] >> sh) & 15u) << 16) | 0x43004300u;
          bp.z = ((p[4] >> sh) & 15u) | (((p[5] >> sh) & 15u) << 16) | 0x43004300u;
          bp.w = ((p[6] >> sh) & 15u) | (((p[7] >> sh) & 15u) << 16) | 0x43004300u;
          acc = __builtin_amdgcn_mfma_f32_32x32x16_bf16(
                    av[i], __builtin_bit_cast(short8, bp), acc, 0, 0, 0);
        }
      }
      // fold: accT += s*acc - s*(128+z)*S_g[row]
      const float t = sc[s2] * (float)(128u + ((zc[s2] >> sh) & 15u));
      float4v Sv[4];
      #pragma unroll
      for (int q = 0; q < 4; ++q)
        Sv[q] = *(const float4v*)(Sg + q*8 + 4*koct);
      #pragma unroll
      for (int r = 0; r < 16; ++r){
        accT[s2][r] = fmaf(sc[s2], acc[r], accT[s2][r]);
        accT[s2][r] = fmaf(-t, Sv[r >> 2][r & 3], accT[s2][r]);
      }
    }
    if (c + 1 < NCH){
      asm volatile("s_waitcnt vmcnt(0)" ::: "memory");   // stage(c+1) landed
      asm volatile("s_waitcnt lgkmcnt(0)" ::: "memory"); // readers drained
      __builtin_amdgcn_s_barrier();
      asm volatile("" ::: "memory");
    }
  }
  // C/D layout (HW-verified m74/m101): col=lane&31, row=(r&3)+8*(r>>2)+4*koct
  #pragma unroll
  for (int s2 = 0; s2 < 2; ++s2){
    const int nn = n0 + w*64 + s2*32 + l31;
    #pragma unroll
    for (int r = 0; r < 16; ++r){
      const int row = (r & 3) + 8*(r >> 2) + 4*koct;
      atomicAdd(out + (size_t)row*N_DIM + nn, accT[s2][r]);
    }
  }
}

extern "C" void kernel_launch(void* const* d_in, const int* in_sizes, int n_in,
                              void* d_out, int out_size, void* d_ws, size_t ws_size,
                              hipStream_t stream)
{
  const float*  x      = (const float*)d_in[0];
  const uint32* qw     = (const uint32*)d_in[1];
  const uint32* qz     = (const uint32*)d_in[2];
  const float*  scales = (const float*)d_in[3];
  const float*  bias   = (const float*)d_in[4];
  const float*  theta  = (const float*)d_in[5];
  const int*    pairs  = (const int*)d_in[6];
  const float*  cs     = (const float*)d_in[7];
  float* out = (float*)d_out;

  prep_kernel<<<dim3(512 + (N_DIM/256)*4), dim3(256), 0, stream>>>(
      x, theta, pairs, cs, bias, out);
  gemm_kernel<<<dim3(NB*KSPLIT), dim3(256), 0, stream>>>(qw, qz, scales, out);
}